// Round 1
// baseline (629.205 us; speedup 1.0000x reference)
//
#include <hip/hip_runtime.h>
#include <cstdint>
#include <cstddef>

// Problem constants
#define NB    8192      // batch
#define NP    4849      // params per item
#define NW    48        // target net width
#define NCH   38        // ceil(NP/128)
#define GY    16        // persistent-gemm grid y; each block does 128/GY = 8 M-tiles

// Tiled intermediate layout: addr(i, rp) = ((rp>>7)*NB + i)*128 + (rp&127)
typedef __attribute__((ext_vector_type(8))) _Float16 f16x8;
typedef __attribute__((ext_vector_type(4))) float f32x4;
typedef __attribute__((ext_vector_type(2))) float f32x2;

__device__ __forceinline__ const float* pptr(const float* Pp, int i, int rp) {
  return Pp + ((size_t)(rp >> 7) * NB + i) * 128 + (rp & 127);
}

__device__ __forceinline__ int invperm(int rp) {
  if (rp >= 96 && rp < 2400) {
    int t = rp - 96; int kb = t / 192; int rem = t - kb * 192;
    return 96 + (rem >> 2) * 48 + (kb * 4 + (rem & 3));
  }
  if (rp >= 2448 && rp < 4752) {
    int t = rp - 2448; int kb = t / 192; int rem = t - kb * 192;
    return 2448 + (rem >> 2) * 48 + (kb * 4 + (rem & 3));
  }
  return rp;
}

// ---------------------------------------------------------------------------
// Kernel 1: PERSISTENT split-fp16 MFMA GEMM (byte-identical to R10).
// At ~60 us real time this sits at the write roofline for the 163 MB
// intermediate (~2.7 TB/s effective); the remainder of the apparent "110 us"
// is the harness's 159 MB d_ws re-poison memset inside every timed replay.
// ---------------------------------------------------------------------------
__global__ __launch_bounds__(256, 2) void hyper_gemm(
    const float* __restrict__ x, const float* __restrict__ c,
    const float* __restrict__ hw1, const float* __restrict__ hb1,
    const float* __restrict__ hw2, const float* __restrict__ hb2,
    float* __restrict__ Pp)
{
  const int t    = threadIdx.x;
  const int lane = t & 63;
  const int wv   = t >> 6;
  const int m16  = lane & 15;
  const int q    = lane >> 4;
  const int rp0  = blockIdx.x * 128;

  const float* wr[2];
  float bias[2];
  #pragma unroll
  for (int nt = 0; nt < 2; ++nt) {
    int rp = rp0 + wv * 32 + nt * 16 + m16;
    int r  = (rp < NP) ? invperm(rp) : 0;
    wr[nt]   = hw2 + (size_t)r * 96;
    bias[nt] = (rp < NP) ? hb2[r] : 0.f;
  }

  f16x8 bh[3][2], bl[3][2];
  #pragma unroll
  for (int ch = 0; ch < 3; ++ch) {
    const int k0 = ch * 32 + q * 8;
    #pragma unroll
    for (int nt = 0; nt < 2; ++nt) {
      float4 f0 = *(const float4*)(wr[nt] + k0);
      float4 f1 = *(const float4*)(wr[nt] + k0 + 4);
      float fv[8] = {f0.x,f0.y,f0.z,f0.w,f1.x,f1.y,f1.z,f1.w};
      #pragma unroll
      for (int e = 0; e < 8; ++e) {
        _Float16 hi = (_Float16)fv[e];
        float r = fv[e] - (float)hi;
        bh[ch][nt][e] = hi;
        bl[ch][nt][e] = (_Float16)r;
      }
    }
  }

  float* cbase = Pp + (size_t)blockIdx.x * NB * 128;

  for (int mtile = blockIdx.y; mtile < 128; mtile += GY) {
    const int i0 = mtile * 64;

    float xv[4], cv[4];
    #pragma unroll
    for (int mt = 0; mt < 4; ++mt) {
      int i = i0 + mt * 16 + m16;
      xv[mt] = x[i]; cv[mt] = c[i];
    }

    f32x4 acc[4][2];
    #pragma unroll
    for (int mt = 0; mt < 4; ++mt)
      #pragma unroll
      for (int nt = 0; nt < 2; ++nt)
        acc[mt][nt] = (f32x4){0.f, 0.f, 0.f, 0.f};

    #pragma unroll
    for (int ch = 0; ch < 3; ++ch) {
      const int k0 = ch * 32 + q * 8;

      float4 A0 = *(const float4*)(hw1 + 2 * k0);
      float4 A1 = *(const float4*)(hw1 + 2 * k0 + 4);
      float4 A2 = *(const float4*)(hw1 + 2 * k0 + 8);
      float4 A3 = *(const float4*)(hw1 + 2 * k0 + 12);
      float4 B0 = *(const float4*)(hb1 + k0);
      float4 B1 = *(const float4*)(hb1 + k0 + 4);
      float w0k[8] = {A0.x,A0.z,A1.x,A1.z,A2.x,A2.z,A3.x,A3.z};
      float w1k[8] = {A0.y,A0.w,A1.y,A1.w,A2.y,A2.w,A3.y,A3.w};
      float bk[8]  = {B0.x,B0.y,B0.z,B0.w,B1.x,B1.y,B1.z,B1.w};

      f16x8 ah[4], al[4];
      #pragma unroll
      for (int mt = 0; mt < 4; ++mt) {
        #pragma unroll
        for (int j = 0; j < 8; ++j) {
          float h = fmaf(xv[mt], w0k[j], fmaf(cv[mt], w1k[j], bk[j]));
          h = h > 0.f ? h : 0.f;
          _Float16 hi = (_Float16)h;
          float r = h - (float)hi;
          ah[mt][j] = hi;
          al[mt][j] = (_Float16)r;
        }
      }

      #pragma unroll
      for (int mt = 0; mt < 4; ++mt)
        #pragma unroll
        for (int nt = 0; nt < 2; ++nt) {
          acc[mt][nt] = __builtin_amdgcn_mfma_f32_16x16x32_f16(al[mt], bl[ch][nt], acc[mt][nt], 0, 0, 0);
          acc[mt][nt] = __builtin_amdgcn_mfma_f32_16x16x32_f16(ah[mt], bl[ch][nt], acc[mt][nt], 0, 0, 0);
          acc[mt][nt] = __builtin_amdgcn_mfma_f32_16x16x32_f16(al[mt], bh[ch][nt], acc[mt][nt], 0, 0, 0);
          acc[mt][nt] = __builtin_amdgcn_mfma_f32_16x16x32_f16(ah[mt], bh[ch][nt], acc[mt][nt], 0, 0, 0);
        }
    }

    #pragma unroll
    for (int nt = 0; nt < 2; ++nt) {
      int off = wv * 32 + nt * 16 + m16;
      if (rp0 + off < NP) {
        #pragma unroll
        for (int mt = 0; mt < 4; ++mt)
          #pragma unroll
          for (int r = 0; r < 4; ++r) {
            int i = i0 + mt * 16 + q * 4 + r;
            cbase[(size_t)i * 128 + off] = acc[mt][nt][r] + bias[nt];
          }
      }
    }
  }
}

// ---------------------------------------------------------------------------
// Kernel 2 (R12): 20-step Adam, TWO items per wave.
// R11 counters: VALUBusy 49%, per-wave VALU-exec model matches measurement
// (~800 exec-cy/step vs ~2500 wall-cy/step) -> one serial chain per wave
// leaves the SIMD half idle. Fix: 2 independent items interleaved in-wave
// (compiler statically fills the stall bubbles), plus serial-path trims:
// raw v_rcp (drop NR + exp clamps), shared per-step bias-correction rcp,
// single packed accumulator per chain (depth-24 pk chain hidden under
// 4-chain issue: 96 instr x 4cy >= 24 x 8cy).
// ---------------------------------------------------------------------------

// x += dpp(x) with add-identity for invalid/masked lanes (LLVM reduce pattern)
#define DPP_ADD(x, ctrl, rmask)                                               \
  (x) += __int_as_float(__builtin_amdgcn_update_dpp(                          \
      0, __float_as_int(x), (ctrl), (rmask), 0xf, false))

__global__ __launch_bounds__(256, 2) void adam_inner(
    const float* __restrict__ Pp, float* __restrict__ out)
{
  __shared__ __align__(16) float hd[4][2][2][96];   // [wave][item][buf][h|dh]

  const int lane = threadIdx.x & 63;
  const int wv   = threadIdx.x >> 6;
  const bool act = lane < NW;

  float w0[2], b0[2], b1v[2], b2v[2], w3[2];
  f32x2 w1p[2][24], w2p[2][24];

  #pragma unroll
  for (int it = 0; it < 2; ++it) {
    const int i = blockIdx.x * 8 + wv * 2 + it;
    w0[it]  = act ? *pptr(Pp, i, lane)        : 0.f;
    b0[it]  = act ? *pptr(Pp, i, 48 + lane)   : 0.f;
    b1v[it] = act ? *pptr(Pp, i, 2400 + lane) : 0.f;
    b2v[it] = act ? *pptr(Pp, i, 4752 + lane) : 0.f;
    w3[it]  = act ? *pptr(Pp, i, 4800 + lane) : 0.f;
    #pragma unroll
    for (int kb = 0; kb < 12; ++kb) {
      float4 q1 = *(const float4*)pptr(Pp, i, 96 + kb * 192 + lane * 4);
      w1p[it][2 * kb]     = (f32x2){q1.x, q1.y};
      w1p[it][2 * kb + 1] = (f32x2){q1.z, q1.w};
      float4 q2 = *(const float4*)pptr(Pp, i, 2448 + kb * 192 + lane * 4);
      w2p[it][2 * kb]     = (f32x2){q2.x, q2.y};
      w2p[it][2 * kb + 1] = (f32x2){q2.z, q2.w};
    }
  }

  float y[2] = {0.f, 0.f}, m[2] = {0.f, 0.f}, v[2] = {0.f, 0.f};
  float b1t = 1.f, b2t = 1.f;

  #pragma unroll 1
  for (int t = 0; t < 20; ++t) {
    // ---- layer 0 (scalar input): lane j computes unit j, both items ----
    #pragma unroll
    for (int it = 0; it < 2; ++it) {
      float z = fmaf(w0[it], y[it], b0[it]);
      float s = __builtin_amdgcn_rcpf(1.f + __expf(-z));
      float h = z * s;
      float dh = fmaf(h, 1.f - s, s) * w0[it];
      if (act) { hd[wv][it][0][lane] = h; hd[wv][it][0][48 + lane] = dh; }
    }

    // ---- layer 1: broadcast-read + packed FMA, items interleaved ----
    f32x2 zz1[2] = {(f32x2){b1v[0], 0.f}, (f32x2){b1v[1], 0.f}};
    f32x2 dd1[2] = {(f32x2){0.f, 0.f}, (f32x2){0.f, 0.f}};
    #pragma unroll
    for (int kk = 0; kk < 12; ++kk) {
      #pragma unroll
      for (int it = 0; it < 2; ++it) {
        float4 ph = *(const float4*)(&hd[wv][it][0][4 * kk]);
        float4 pd = *(const float4*)(&hd[wv][it][0][48 + 4 * kk]);
        zz1[it] = __builtin_elementwise_fma(w1p[it][2 * kk],     (f32x2){ph.x, ph.y}, zz1[it]);
        zz1[it] = __builtin_elementwise_fma(w1p[it][2 * kk + 1], (f32x2){ph.z, ph.w}, zz1[it]);
        dd1[it] = __builtin_elementwise_fma(w1p[it][2 * kk],     (f32x2){pd.x, pd.y}, dd1[it]);
        dd1[it] = __builtin_elementwise_fma(w1p[it][2 * kk + 1], (f32x2){pd.z, pd.w}, dd1[it]);
      }
    }
    #pragma unroll
    for (int it = 0; it < 2; ++it) {
      float z1  = zz1[it].x + zz1[it].y;
      float dz1 = dd1[it].x + dd1[it].y;
      float s = __builtin_amdgcn_rcpf(1.f + __expf(-z1));
      float h = z1 * s;
      float dh = fmaf(h, 1.f - s, s) * dz1;
      if (act) { hd[wv][it][1][lane] = h; hd[wv][it][1][48 + lane] = dh; }
    }

    // ---- layer 2 ----
    f32x2 zz2[2] = {(f32x2){b2v[0], 0.f}, (f32x2){b2v[1], 0.f}};
    f32x2 dd2[2] = {(f32x2){0.f, 0.f}, (f32x2){0.f, 0.f}};
    #pragma unroll
    for (int kk = 0; kk < 12; ++kk) {
      #pragma unroll
      for (int it = 0; it < 2; ++it) {
        float4 ph = *(const float4*)(&hd[wv][it][1][4 * kk]);
        float4 pd = *(const float4*)(&hd[wv][it][1][48 + 4 * kk]);
        zz2[it] = __builtin_elementwise_fma(w2p[it][2 * kk],     (f32x2){ph.x, ph.y}, zz2[it]);
        zz2[it] = __builtin_elementwise_fma(w2p[it][2 * kk + 1], (f32x2){ph.z, ph.w}, zz2[it]);
        dd2[it] = __builtin_elementwise_fma(w2p[it][2 * kk],     (f32x2){pd.x, pd.y}, dd2[it]);
        dd2[it] = __builtin_elementwise_fma(w2p[it][2 * kk + 1], (f32x2){pd.z, pd.w}, dd2[it]);
      }
    }

    float g[2];
    #pragma unroll
    for (int it = 0; it < 2; ++it) {
      float z2  = zz2[it].x + zz2[it].y;
      float dz2 = dd2[it].x + dd2[it].y;
      float s = __builtin_amdgcn_rcpf(1.f + __expf(-z2));
      float dh = fmaf(z2 * s, 1.f - s, s) * dz2;

      // ---- g = w3 . dh3 : DPP reduction (VALU pipe, no DS ops) ----
      float r = act ? w3[it] * dh : 0.f;
      DPP_ADD(r, 0x111, 0xf);   // row_shr:1
      DPP_ADD(r, 0x112, 0xf);   // row_shr:2
      DPP_ADD(r, 0x114, 0xf);   // row_shr:4
      DPP_ADD(r, 0x118, 0xf);   // row_shr:8  -> lane15 of each row = row sum
      DPP_ADD(r, 0x142, 0xa);   // row_bcast:15 into rows 1,3
      DPP_ADD(r, 0x143, 0xc);   // row_bcast:31 into rows 2,3 -> lane63 = total
      g[it] = __int_as_float(__builtin_amdgcn_readlane(__float_as_int(r), 63));
    }

    // ---- Adam update (bias-correction shared across items) ----
    b1t *= 0.9f; b2t *= 0.999f;
    float c1 = __builtin_amdgcn_rcpf(1.f - b1t);
    float c2 = __builtin_amdgcn_rcpf(1.f - b2t);
    #pragma unroll
    for (int it = 0; it < 2; ++it) {
      m[it] = fmaf(0.9f,   m[it], 0.1f   * g[it]);
      v[it] = fmaf(0.999f, v[it], 0.001f * g[it] * g[it]);
      float mh  = m[it] * c1;
      float vh  = v[it] * c2;
      float den = __builtin_amdgcn_sqrtf(vh) + 1e-8f;
      y[it] -= 0.1f * mh * __builtin_amdgcn_rcpf(den);
    }
  }

  if (lane == 0) {
    out[blockIdx.x * 8 + wv * 2]     = y[0];
    out[blockIdx.x * 8 + wv * 2 + 1] = y[1];
  }
}

// ---------------------------------------------------------------------------
extern "C" void kernel_launch(void* const* d_in, const int* in_sizes, int n_in,
                              void* d_out, int out_size, void* d_ws, size_t ws_size,
                              hipStream_t stream) {
  const float* x   = (const float*)d_in[0];
  const float* c   = (const float*)d_in[1];
  const float* hw1 = (const float*)d_in[2];
  const float* hb1 = (const float*)d_in[3];
  const float* hw2 = (const float*)d_in[4];
  const float* hb2 = (const float*)d_in[5];
  float* Pp  = (float*)d_ws;   // NCH*NB*128*4 = 159,383,552 bytes
  float* out = (float*)d_out;

  dim3 gridB(NCH, GY);         // 38 x 16 persistent blocks
  hyper_gemm<<<gridB, dim3(256), 0, stream>>>(x, c, hw1, hb1, hw2, hb2, Pp);
  adam_inner<<<dim3(1024), dim3(256), 0, stream>>>(Pp, out);
}

// Round 2
// 460.581 us; speedup vs baseline: 1.3661x; 1.3661x over previous
//
#include <hip/hip_runtime.h>
#include <cstdint>
#include <cstddef>

// Problem constants
#define NB    8192      // batch
#define NP    4849      // params per item
#define NW    48        // target net width
#define NCH   38        // ceil(NP/128)
#define GY    16        // persistent-gemm grid y; each block does 128/GY = 8 M-tiles

// Tiled intermediate layout: addr(i, rp) = ((rp>>7)*NB + i)*128 + (rp&127)
typedef __attribute__((ext_vector_type(8))) _Float16 f16x8;
typedef __attribute__((ext_vector_type(4))) float f32x4;
typedef __attribute__((ext_vector_type(2))) float f32x2;

__device__ __forceinline__ const float* pptr(const float* Pp, int i, int rp) {
  return Pp + ((size_t)(rp >> 7) * NB + i) * 128 + (rp & 127);
}

__device__ __forceinline__ int invperm(int rp) {
  if (rp >= 96 && rp < 2400) {
    int t = rp - 96; int kb = t / 192; int rem = t - kb * 192;
    return 96 + (rem >> 2) * 48 + (kb * 4 + (rem & 3));
  }
  if (rp >= 2448 && rp < 4752) {
    int t = rp - 2448; int kb = t / 192; int rem = t - kb * 192;
    return 2448 + (rem >> 2) * 48 + (kb * 4 + (rem & 3));
  }
  return rp;
}

// ---------------------------------------------------------------------------
// Kernel 1: PERSISTENT split-fp16 MFMA GEMM (byte-identical to R10).
// At ~60 us real time this sits at the write roofline for the 163 MB
// intermediate (~2.7 TB/s effective); the remainder of the apparent "110 us"
// is the harness's 159 MB d_ws re-poison memset inside every timed replay.
// ---------------------------------------------------------------------------
__global__ __launch_bounds__(256, 2) void hyper_gemm(
    const float* __restrict__ x, const float* __restrict__ c,
    const float* __restrict__ hw1, const float* __restrict__ hb1,
    const float* __restrict__ hw2, const float* __restrict__ hb2,
    float* __restrict__ Pp)
{
  const int t    = threadIdx.x;
  const int lane = t & 63;
  const int wv   = t >> 6;
  const int m16  = lane & 15;
  const int q    = lane >> 4;
  const int rp0  = blockIdx.x * 128;

  const float* wr[2];
  float bias[2];
  #pragma unroll
  for (int nt = 0; nt < 2; ++nt) {
    int rp = rp0 + wv * 32 + nt * 16 + m16;
    int r  = (rp < NP) ? invperm(rp) : 0;
    wr[nt]   = hw2 + (size_t)r * 96;
    bias[nt] = (rp < NP) ? hb2[r] : 0.f;
  }

  f16x8 bh[3][2], bl[3][2];
  #pragma unroll
  for (int ch = 0; ch < 3; ++ch) {
    const int k0 = ch * 32 + q * 8;
    #pragma unroll
    for (int nt = 0; nt < 2; ++nt) {
      float4 f0 = *(const float4*)(wr[nt] + k0);
      float4 f1 = *(const float4*)(wr[nt] + k0 + 4);
      float fv[8] = {f0.x,f0.y,f0.z,f0.w,f1.x,f1.y,f1.z,f1.w};
      #pragma unroll
      for (int e = 0; e < 8; ++e) {
        _Float16 hi = (_Float16)fv[e];
        float r = fv[e] - (float)hi;
        bh[ch][nt][e] = hi;
        bl[ch][nt][e] = (_Float16)r;
      }
    }
  }

  float* cbase = Pp + (size_t)blockIdx.x * NB * 128;

  for (int mtile = blockIdx.y; mtile < 128; mtile += GY) {
    const int i0 = mtile * 64;

    float xv[4], cv[4];
    #pragma unroll
    for (int mt = 0; mt < 4; ++mt) {
      int i = i0 + mt * 16 + m16;
      xv[mt] = x[i]; cv[mt] = c[i];
    }

    f32x4 acc[4][2];
    #pragma unroll
    for (int mt = 0; mt < 4; ++mt)
      #pragma unroll
      for (int nt = 0; nt < 2; ++nt)
        acc[mt][nt] = (f32x4){0.f, 0.f, 0.f, 0.f};

    #pragma unroll
    for (int ch = 0; ch < 3; ++ch) {
      const int k0 = ch * 32 + q * 8;

      float4 A0 = *(const float4*)(hw1 + 2 * k0);
      float4 A1 = *(const float4*)(hw1 + 2 * k0 + 4);
      float4 A2 = *(const float4*)(hw1 + 2 * k0 + 8);
      float4 A3 = *(const float4*)(hw1 + 2 * k0 + 12);
      float4 B0 = *(const float4*)(hb1 + k0);
      float4 B1 = *(const float4*)(hb1 + k0 + 4);
      float w0k[8] = {A0.x,A0.z,A1.x,A1.z,A2.x,A2.z,A3.x,A3.z};
      float w1k[8] = {A0.y,A0.w,A1.y,A1.w,A2.y,A2.w,A3.y,A3.w};
      float bk[8]  = {B0.x,B0.y,B0.z,B0.w,B1.x,B1.y,B1.z,B1.w};

      f16x8 ah[4], al[4];
      #pragma unroll
      for (int mt = 0; mt < 4; ++mt) {
        #pragma unroll
        for (int j = 0; j < 8; ++j) {
          float h = fmaf(xv[mt], w0k[j], fmaf(cv[mt], w1k[j], bk[j]));
          h = h > 0.f ? h : 0.f;
          _Float16 hi = (_Float16)h;
          float r = h - (float)hi;
          ah[mt][j] = hi;
          al[mt][j] = (_Float16)r;
        }
      }

      #pragma unroll
      for (int mt = 0; mt < 4; ++mt)
        #pragma unroll
        for (int nt = 0; nt < 2; ++nt) {
          acc[mt][nt] = __builtin_amdgcn_mfma_f32_16x16x32_f16(al[mt], bl[ch][nt], acc[mt][nt], 0, 0, 0);
          acc[mt][nt] = __builtin_amdgcn_mfma_f32_16x16x32_f16(ah[mt], bl[ch][nt], acc[mt][nt], 0, 0, 0);
          acc[mt][nt] = __builtin_amdgcn_mfma_f32_16x16x32_f16(al[mt], bh[ch][nt], acc[mt][nt], 0, 0, 0);
          acc[mt][nt] = __builtin_amdgcn_mfma_f32_16x16x32_f16(ah[mt], bh[ch][nt], acc[mt][nt], 0, 0, 0);
        }
    }

    #pragma unroll
    for (int nt = 0; nt < 2; ++nt) {
      int off = wv * 32 + nt * 16 + m16;
      if (rp0 + off < NP) {
        #pragma unroll
        for (int mt = 0; mt < 4; ++mt)
          #pragma unroll
          for (int r = 0; r < 4; ++r) {
            int i = i0 + mt * 16 + q * 4 + r;
            cbase[(size_t)i * 128 + off] = acc[mt][nt][r] + bias[nt];
          }
      }
    }
  }
}

// ---------------------------------------------------------------------------
// Kernel 2 (R13): 20-step Adam, ONE item per 64-thread block.
// R12 post-mortem: 2 items/wave needs 192 weight VGPRs; allocator kept 128
// and scratch-spilled (FETCH 79MB -> 1.7GB, VALUBusy 8.8%). Reverted to the
// proven 1-item body (108 VGPR, no spill).
// R11 residency analysis: VALUBusy 49% / occupancy ~19% is consistent with
// only 2 waves/SIMD resident (2 x 800 issue-cy / 3360 wall-cy = 48%) even
// though 108 VGPR permits 4. Fix attempt: 64-thread blocks (1 wave = 1 item,
// grid 8192) + __launch_bounds__(64,4) -> residency no longer quantized to
// 4-wave workgroups; target 4 independent chains per SIMD.
// Numerics: raw v_rcp (no NR, no exp clamps) validated by R12's pass.
// ---------------------------------------------------------------------------

// x += dpp(x) with add-identity for invalid/masked lanes (LLVM reduce pattern)
#define DPP_ADD(x, ctrl, rmask)                                               \
  (x) += __int_as_float(__builtin_amdgcn_update_dpp(                          \
      0, __float_as_int(x), (ctrl), (rmask), 0xf, false))

__global__ __launch_bounds__(64, 4) void adam_inner(
    const float* __restrict__ Pp, float* __restrict__ out)
{
  __shared__ __align__(16) float hd[2][96];   // [buf][h(48)|dh(48)]

  const int lane = threadIdx.x;
  const int i    = blockIdx.x;
  const bool act = lane < NW;

  float* buf0 = &hd[0][0];
  float* buf1 = &hd[1][0];

  float w0  = act ? *pptr(Pp, i, lane)        : 0.f;
  float b0  = act ? *pptr(Pp, i, 48 + lane)   : 0.f;
  float b1v = act ? *pptr(Pp, i, 2400 + lane) : 0.f;
  float b2v = act ? *pptr(Pp, i, 4752 + lane) : 0.f;
  float w3  = act ? *pptr(Pp, i, 4800 + lane) : 0.f;

  f32x2 w1p[24], w2p[24];
  #pragma unroll
  for (int kb = 0; kb < 12; ++kb) {
    float4 q1 = *(const float4*)pptr(Pp, i, 96 + kb * 192 + lane * 4);
    w1p[2 * kb]     = (f32x2){q1.x, q1.y};
    w1p[2 * kb + 1] = (f32x2){q1.z, q1.w};
    float4 q2 = *(const float4*)pptr(Pp, i, 2448 + kb * 192 + lane * 4);
    w2p[2 * kb]     = (f32x2){q2.x, q2.y};
    w2p[2 * kb + 1] = (f32x2){q2.z, q2.w};
  }

  float y = 0.f, m = 0.f, v = 0.f;
  float b1t = 1.f, b2t = 1.f;

  #pragma unroll 1
  for (int t = 0; t < 20; ++t) {
    // ---- layer 0 (scalar input): lane j computes unit j ----
    float z  = fmaf(w0, y, b0);
    float s  = __builtin_amdgcn_rcpf(1.f + __expf(-z));
    float h  = z * s;
    float dh = fmaf(z * s, 1.f - s, s) * w0;
    if (act) { buf0[lane] = h; buf0[48 + lane] = dh; }

    // ---- layer 1: prefetch ALL broadcast reads, then indep chains ----
    float4 ph[12], pd[12];
    #pragma unroll
    for (int kk = 0; kk < 12; ++kk) {
      ph[kk] = *(const float4*)(buf0 + 4 * kk);
      pd[kk] = *(const float4*)(buf0 + 48 + 4 * kk);
    }
    {
      f32x2 zz[4] = {(f32x2){b1v, 0.f}, (f32x2){0.f, 0.f},
                     (f32x2){0.f, 0.f}, (f32x2){0.f, 0.f}};
      f32x2 dd[4] = {(f32x2){0.f, 0.f}, (f32x2){0.f, 0.f},
                     (f32x2){0.f, 0.f}, (f32x2){0.f, 0.f}};
      #pragma unroll
      for (int kk = 0; kk < 12; ++kk) {
        int c0 = (2 * kk) & 3, c1 = (2 * kk + 1) & 3;
        zz[c0] = __builtin_elementwise_fma(w1p[2 * kk],     (f32x2){ph[kk].x, ph[kk].y}, zz[c0]);
        zz[c1] = __builtin_elementwise_fma(w1p[2 * kk + 1], (f32x2){ph[kk].z, ph[kk].w}, zz[c1]);
        dd[c0] = __builtin_elementwise_fma(w1p[2 * kk],     (f32x2){pd[kk].x, pd[kk].y}, dd[c0]);
        dd[c1] = __builtin_elementwise_fma(w1p[2 * kk + 1], (f32x2){pd[kk].z, pd[kk].w}, dd[c1]);
      }
      f32x2 zs = (zz[0] + zz[1]) + (zz[2] + zz[3]);
      f32x2 ds = (dd[0] + dd[1]) + (dd[2] + dd[3]);
      float z1  = zs.x + zs.y;
      float dz1 = ds.x + ds.y;

      s  = __builtin_amdgcn_rcpf(1.f + __expf(-z1));
      h  = z1 * s;
      dh = fmaf(h, 1.f - s, s) * dz1;
    }
    if (act) { buf1[lane] = h; buf1[48 + lane] = dh; }

    // ---- layer 2 ----
    #pragma unroll
    for (int kk = 0; kk < 12; ++kk) {
      ph[kk] = *(const float4*)(buf1 + 4 * kk);
      pd[kk] = *(const float4*)(buf1 + 48 + 4 * kk);
    }
    {
      f32x2 zz[4] = {(f32x2){b2v, 0.f}, (f32x2){0.f, 0.f},
                     (f32x2){0.f, 0.f}, (f32x2){0.f, 0.f}};
      f32x2 dd[4] = {(f32x2){0.f, 0.f}, (f32x2){0.f, 0.f},
                     (f32x2){0.f, 0.f}, (f32x2){0.f, 0.f}};
      #pragma unroll
      for (int kk = 0; kk < 12; ++kk) {
        int c0 = (2 * kk) & 3, c1 = (2 * kk + 1) & 3;
        zz[c0] = __builtin_elementwise_fma(w2p[2 * kk],     (f32x2){ph[kk].x, ph[kk].y}, zz[c0]);
        zz[c1] = __builtin_elementwise_fma(w2p[2 * kk + 1], (f32x2){ph[kk].z, ph[kk].w}, zz[c1]);
        dd[c0] = __builtin_elementwise_fma(w2p[2 * kk],     (f32x2){pd[kk].x, pd[kk].y}, dd[c0]);
        dd[c1] = __builtin_elementwise_fma(w2p[2 * kk + 1], (f32x2){pd[kk].z, pd[kk].w}, dd[c1]);
      }
      f32x2 zs = (zz[0] + zz[1]) + (zz[2] + zz[3]);
      f32x2 ds = (dd[0] + dd[1]) + (dd[2] + dd[3]);
      float z2  = zs.x + zs.y;
      float dz2 = ds.x + ds.y;

      s  = __builtin_amdgcn_rcpf(1.f + __expf(-z2));
      dh = fmaf(z2 * s, 1.f - s, s) * dz2;
    }

    // ---- g = w3 . dh3 : DPP reduction (VALU pipe, no DS ops) ----
    float r = act ? w3 * dh : 0.f;
    DPP_ADD(r, 0x111, 0xf);   // row_shr:1
    DPP_ADD(r, 0x112, 0xf);   // row_shr:2
    DPP_ADD(r, 0x114, 0xf);   // row_shr:4
    DPP_ADD(r, 0x118, 0xf);   // row_shr:8  -> lane15 of each row = row sum
    DPP_ADD(r, 0x142, 0xa);   // row_bcast:15 into rows 1,3
    DPP_ADD(r, 0x143, 0xc);   // row_bcast:31 into rows 2,3 -> lane63 = total
    float g = __int_as_float(__builtin_amdgcn_readlane(__float_as_int(r), 63));

    // ---- Adam update (replicated per lane) ----
    m = fmaf(0.9f,   m, 0.1f   * g);
    v = fmaf(0.999f, v, 0.001f * g * g);
    b1t *= 0.9f; b2t *= 0.999f;
    float mh  = m * __builtin_amdgcn_rcpf(1.f - b1t);
    float vh  = v * __builtin_amdgcn_rcpf(1.f - b2t);
    float den = __builtin_amdgcn_sqrtf(vh) + 1e-8f;
    y -= 0.1f * mh * __builtin_amdgcn_rcpf(den);
  }

  if (lane == 0) out[i] = y;
}

// ---------------------------------------------------------------------------
extern "C" void kernel_launch(void* const* d_in, const int* in_sizes, int n_in,
                              void* d_out, int out_size, void* d_ws, size_t ws_size,
                              hipStream_t stream) {
  const float* x   = (const float*)d_in[0];
  const float* c   = (const float*)d_in[1];
  const float* hw1 = (const float*)d_in[2];
  const float* hb1 = (const float*)d_in[3];
  const float* hw2 = (const float*)d_in[4];
  const float* hb2 = (const float*)d_in[5];
  float* Pp  = (float*)d_ws;   // NCH*NB*128*4 = 159,383,552 bytes
  float* out = (float*)d_out;

  dim3 gridB(NCH, GY);         // 38 x 16 persistent blocks
  hyper_gemm<<<gridB, dim3(256), 0, stream>>>(x, c, hw1, hb1, hw2, hb2, Pp);
  adam_inner<<<dim3(8192), dim3(64), 0, stream>>>(Pp, out);
}

// Round 6
// 237.262 us; speedup vs baseline: 2.6519x; 1.9412x over previous
//
#include <hip/hip_runtime.h>
#include <cstdint>
#include <cstddef>

// Problem constants
#define NB    8192      // batch
#define NP    4849      // params per item
#define NW    48        // target net width
#define NCH   38        // ceil(NP/128)
#define GY    16        // persistent-gemm grid y; each block does 128/GY = 8 M-tiles

// Tiled intermediate layout: addr(i, rp) = ((rp>>7)*NB + i)*128 + (rp&127)
typedef __attribute__((ext_vector_type(8))) _Float16 f16x8;
typedef __attribute__((ext_vector_type(4))) float f32x4;
typedef __attribute__((ext_vector_type(2))) float f32x2;

__device__ __forceinline__ const float* pptr(const float* Pp, int i, int rp) {
  return Pp + ((size_t)(rp >> 7) * NB + i) * 128 + (rp & 127);
}

__device__ __forceinline__ int invperm(int rp) {
  if (rp >= 96 && rp < 2400) {
    int t = rp - 96; int kb = t / 192; int rem = t - kb * 192;
    return 96 + (rem >> 2) * 48 + (kb * 4 + (rem & 3));
  }
  if (rp >= 2448 && rp < 4752) {
    int t = rp - 2448; int kb = t / 192; int rem = t - kb * 192;
    return 2448 + (rem >> 2) * 48 + (kb * 4 + (rem & 3));
  }
  return rp;
}

// ---------------------------------------------------------------------------
// Kernel 1: PERSISTENT split-fp16 MFMA GEMM (byte-identical to R10).
// ---------------------------------------------------------------------------
__global__ __launch_bounds__(256, 2) void hyper_gemm(
    const float* __restrict__ x, const float* __restrict__ c,
    const float* __restrict__ hw1, const float* __restrict__ hb1,
    const float* __restrict__ hw2, const float* __restrict__ hb2,
    float* __restrict__ Pp)
{
  const int t    = threadIdx.x;
  const int lane = t & 63;
  const int wv   = t >> 6;
  const int m16  = lane & 15;
  const int q    = lane >> 4;
  const int rp0  = blockIdx.x * 128;

  const float* wr[2];
  float bias[2];
  #pragma unroll
  for (int nt = 0; nt < 2; ++nt) {
    int rp = rp0 + wv * 32 + nt * 16 + m16;
    int r  = (rp < NP) ? invperm(rp) : 0;
    wr[nt]   = hw2 + (size_t)r * 96;
    bias[nt] = (rp < NP) ? hb2[r] : 0.f;
  }

  f16x8 bh[3][2], bl[3][2];
  #pragma unroll
  for (int ch = 0; ch < 3; ++ch) {
    const int k0 = ch * 32 + q * 8;
    #pragma unroll
    for (int nt = 0; nt < 2; ++nt) {
      float4 f0 = *(const float4*)(wr[nt] + k0);
      float4 f1 = *(const float4*)(wr[nt] + k0 + 4);
      float fv[8] = {f0.x,f0.y,f0.z,f0.w,f1.x,f1.y,f1.z,f1.w};
      #pragma unroll
      for (int e = 0; e < 8; ++e) {
        _Float16 hi = (_Float16)fv[e];
        float r = fv[e] - (float)hi;
        bh[ch][nt][e] = hi;
        bl[ch][nt][e] = (_Float16)r;
      }
    }
  }

  float* cbase = Pp + (size_t)blockIdx.x * NB * 128;

  for (int mtile = blockIdx.y; mtile < 128; mtile += GY) {
    const int i0 = mtile * 64;

    float xv[4], cv[4];
    #pragma unroll
    for (int mt = 0; mt < 4; ++mt) {
      int i = i0 + mt * 16 + m16;
      xv[mt] = x[i]; cv[mt] = c[i];
    }

    f32x4 acc[4][2];
    #pragma unroll
    for (int mt = 0; mt < 4; ++mt)
      #pragma unroll
      for (int nt = 0; nt < 2; ++nt)
        acc[mt][nt] = (f32x4){0.f, 0.f, 0.f, 0.f};

    #pragma unroll
    for (int ch = 0; ch < 3; ++ch) {
      const int k0 = ch * 32 + q * 8;

      float4 A0 = *(const float4*)(hw1 + 2 * k0);
      float4 A1 = *(const float4*)(hw1 + 2 * k0 + 4);
      float4 A2 = *(const float4*)(hw1 + 2 * k0 + 8);
      float4 A3 = *(const float4*)(hw1 + 2 * k0 + 12);
      float4 B0 = *(const float4*)(hb1 + k0);
      float4 B1 = *(const float4*)(hb1 + k0 + 4);
      float w0k[8] = {A0.x,A0.z,A1.x,A1.z,A2.x,A2.z,A3.x,A3.z};
      float w1k[8] = {A0.y,A0.w,A1.y,A1.w,A2.y,A2.w,A3.y,A3.w};
      float bk[8]  = {B0.x,B0.y,B0.z,B0.w,B1.x,B1.y,B1.z,B1.w};

      f16x8 ah[4], al[4];
      #pragma unroll
      for (int mt = 0; mt < 4; ++mt) {
        #pragma unroll
        for (int j = 0; j < 8; ++j) {
          float h = fmaf(xv[mt], w0k[j], fmaf(cv[mt], w1k[j], bk[j]));
          h = h > 0.f ? h : 0.f;
          _Float16 hi = (_Float16)h;
          float r = h - (float)hi;
          ah[mt][j] = hi;
          al[mt][j] = (_Float16)r;
        }
      }

      #pragma unroll
      for (int mt = 0; mt < 4; ++mt)
        #pragma unroll
        for (int nt = 0; nt < 2; ++nt) {
          acc[mt][nt] = __builtin_amdgcn_mfma_f32_16x16x32_f16(al[mt], bl[ch][nt], acc[mt][nt], 0, 0, 0);
          acc[mt][nt] = __builtin_amdgcn_mfma_f32_16x16x32_f16(ah[mt], bl[ch][nt], acc[mt][nt], 0, 0, 0);
          acc[mt][nt] = __builtin_amdgcn_mfma_f32_16x16x32_f16(al[mt], bh[ch][nt], acc[mt][nt], 0, 0, 0);
          acc[mt][nt] = __builtin_amdgcn_mfma_f32_16x16x32_f16(ah[mt], bh[ch][nt], acc[mt][nt], 0, 0, 0);
        }
    }

    #pragma unroll
    for (int nt = 0; nt < 2; ++nt) {
      int off = wv * 32 + nt * 16 + m16;
      if (rp0 + off < NP) {
        #pragma unroll
        for (int mt = 0; mt < 4; ++mt)
          #pragma unroll
          for (int r = 0; r < 4; ++r) {
            int i = i0 + mt * 16 + q * 4 + r;
            cbase[(size_t)i * 128 + off] = acc[mt][nt][r] + bias[nt];
          }
      }
    }
  }
}

// ---------------------------------------------------------------------------
// Kernel 2 (R17): ZERO-LDS 20-step Adam, one item per wave.
// R15/R16 (MFMA relayout) failed identically -> abandoned. This keeps R11's
// validated math/registers but replaces the LDS h/dh broadcast (48 bcast
// ds_read_b128 + writes per step = DS-pipe serializer, VALUBusy capped 49%)
// with v_readlane broadcasts: lane j holds h_j/dh_j and W[j][k]; each h_k,
// dh_k is pulled to an SGPR (SALU pipe, parallel to VALU) and consumed by
// scalar-operand FMAs. 0 DS ops/step. All primitives validated in R11/R13.
// ---------------------------------------------------------------------------

#define DPP_ADD(x, ctrl, rmask)                                               \
  (x) += __int_as_float(__builtin_amdgcn_update_dpp(                          \
      0, __float_as_int(x), (ctrl), (rmask), 0xf, false))

#define RDLANE(x, k) __int_as_float(__builtin_amdgcn_readlane(__float_as_int(x), (k)))

__global__ __launch_bounds__(256, 2) void adam_inner(
    const float* __restrict__ Pp, float* __restrict__ out)
{
  const int lane = threadIdx.x & 63;
  const int wv   = threadIdx.x >> 6;
  const int i    = blockIdx.x * 4 + wv;
  const bool act = lane < NW;

  float w0  = act ? *pptr(Pp, i, lane)        : 0.f;
  float b0  = act ? *pptr(Pp, i, 48 + lane)   : 0.f;
  float b1v = act ? *pptr(Pp, i, 2400 + lane) : 0.f;
  float b2v = act ? *pptr(Pp, i, 4752 + lane) : 0.f;
  float w3  = act ? *pptr(Pp, i, 4800 + lane) : 0.f;

  // lane j holds W1[j][k], W2[j][k] for k=0..47 as f32x2 pairs (R11 gather)
  f32x2 w1p[24], w2p[24];
  #pragma unroll
  for (int kb = 0; kb < 12; ++kb) {
    float4 q1 = *(const float4*)pptr(Pp, i, 96 + kb * 192 + lane * 4);
    w1p[2 * kb]     = (f32x2){q1.x, q1.y};
    w1p[2 * kb + 1] = (f32x2){q1.z, q1.w};
    float4 q2 = *(const float4*)pptr(Pp, i, 2448 + kb * 192 + lane * 4);
    w2p[2 * kb]     = (f32x2){q2.x, q2.y};
    w2p[2 * kb + 1] = (f32x2){q2.z, q2.w};
  }

  float y = 0.f, m = 0.f, v = 0.f;
  float b1t = 1.f, b2t = 1.f;

  #pragma unroll 1
  for (int t = 0; t < 20; ++t) {
    // ---- L0 (in-lane): lane j computes h1_j, dh1_j ----
    float z  = fmaf(w0, y, b0);
    float s  = __builtin_amdgcn_rcpf(1.f + __expf(-z));
    float h1 = z * s;
    float dh1 = fmaf(h1, 1.f - s, s) * w0;

    // ---- L1: z1_j = sum_k W1[j][k] h1_k + b1_j ; dz1_j = sum_k W1[j][k] dh1_k
    // h1_k/dh1_k broadcast via readlane (SALU), 2 accum chains each ----
    float za = b1v, zb = 0.f, da = 0.f, db = 0.f;
    #pragma unroll
    for (int k2 = 0; k2 < 24; ++k2) {
      float hk0 = RDLANE(h1,  2 * k2);
      float hk1 = RDLANE(h1,  2 * k2 + 1);
      float dk0 = RDLANE(dh1, 2 * k2);
      float dk1 = RDLANE(dh1, 2 * k2 + 1);
      za = fmaf(w1p[k2].x, hk0, za);
      zb = fmaf(w1p[k2].y, hk1, zb);
      da = fmaf(w1p[k2].x, dk0, da);
      db = fmaf(w1p[k2].y, dk1, db);
    }
    float z1  = za + zb;
    float dz1 = da + db;

    // ---- mid sigma (in-lane) ----
    s = __builtin_amdgcn_rcpf(1.f + __expf(-z1));
    float h2  = z1 * s;
    float dh2 = fmaf(h2, 1.f - s, s) * dz1;

    // ---- L2 ----
    za = b2v; zb = 0.f; da = 0.f; db = 0.f;
    #pragma unroll
    for (int k2 = 0; k2 < 24; ++k2) {
      float hk0 = RDLANE(h2,  2 * k2);
      float hk1 = RDLANE(h2,  2 * k2 + 1);
      float dk0 = RDLANE(dh2, 2 * k2);
      float dk1 = RDLANE(dh2, 2 * k2 + 1);
      za = fmaf(w2p[k2].x, hk0, za);
      zb = fmaf(w2p[k2].y, hk1, zb);
      da = fmaf(w2p[k2].x, dk0, da);
      db = fmaf(w2p[k2].y, dk1, db);
    }
    float z2  = za + zb;
    float dz2 = da + db;

    // ---- final sigma + g = w3 . dh3 (DPP reduce over 64 lanes, as R11) ----
    s = __builtin_amdgcn_rcpf(1.f + __expf(-z2));
    float dh3 = fmaf(z2 * s, 1.f - s, s) * dz2;

    float r = act ? w3 * dh3 : 0.f;
    DPP_ADD(r, 0x111, 0xf);   // row_shr:1
    DPP_ADD(r, 0x112, 0xf);   // row_shr:2
    DPP_ADD(r, 0x114, 0xf);   // row_shr:4
    DPP_ADD(r, 0x118, 0xf);   // row_shr:8  -> lane15 of each row = row sum
    DPP_ADD(r, 0x142, 0xa);   // row_bcast:15 into rows 1,3
    DPP_ADD(r, 0x143, 0xc);   // row_bcast:31 into rows 2,3 -> lane63 = total
    float g = RDLANE(r, 63);

    // ---- Adam update (replicated per lane) ----
    m = fmaf(0.9f,   m, 0.1f   * g);
    v = fmaf(0.999f, v, 0.001f * g * g);
    b1t *= 0.9f; b2t *= 0.999f;
    float mh  = m * __builtin_amdgcn_rcpf(1.f - b1t);
    float vh  = v * __builtin_amdgcn_rcpf(1.f - b2t);
    float den = __builtin_amdgcn_sqrtf(vh) + 1e-8f;
    y -= 0.1f * mh * __builtin_amdgcn_rcpf(den);
  }

  if (lane == 0) out[i] = y;
}

// ---------------------------------------------------------------------------
extern "C" void kernel_launch(void* const* d_in, const int* in_sizes, int n_in,
                              void* d_out, int out_size, void* d_ws, size_t ws_size,
                              hipStream_t stream) {
  const float* x   = (const float*)d_in[0];
  const float* c   = (const float*)d_in[1];
  const float* hw1 = (const float*)d_in[2];
  const float* hb1 = (const float*)d_in[3];
  const float* hw2 = (const float*)d_in[4];
  const float* hb2 = (const float*)d_in[5];
  float* Pp  = (float*)d_ws;   // NCH*NB*128*4 = 159,383,552 bytes
  float* out = (float*)d_out;

  dim3 gridB(NCH, GY);         // 38 x 16 persistent blocks
  hyper_gemm<<<gridB, dim3(256), 0, stream>>>(x, c, hw1, hb1, hw2, hb2, Pp);
  adam_inner<<<dim3(2048), dim3(256), 0, stream>>>(Pp, out);
}

// Round 7
// 204.258 us; speedup vs baseline: 3.0804x; 1.1616x over previous
//
#include <hip/hip_runtime.h>
#include <cstdint>
#include <cstddef>

// Problem constants
#define NB    8192      // batch
#define NP    4849      // params per item
#define NW    48        // target net width
#define NCH   38        // ceil(NP/128)
#define GY    64        // gemm grid y; each block does 128/GY = 2 M-tiles

// Tiled intermediate layout: addr(i, rp) = ((rp>>7)*NB + i)*128 + (rp&127)
typedef __attribute__((ext_vector_type(8))) _Float16 f16x8;
typedef __attribute__((ext_vector_type(4))) float f32x4;
typedef __attribute__((ext_vector_type(2))) float f32x2;

__device__ __forceinline__ const float* pptr(const float* Pp, int i, int rp) {
  return Pp + ((size_t)(rp >> 7) * NB + i) * 128 + (rp & 127);
}

__device__ __forceinline__ int invperm(int rp) {
  if (rp >= 96 && rp < 2400) {
    int t = rp - 96; int kb = t / 192; int rem = t - kb * 192;
    return 96 + (rem >> 2) * 48 + (kb * 4 + (rem & 3));
  }
  if (rp >= 2448 && rp < 4752) {
    int t = rp - 2448; int kb = t / 192; int rem = t - kb * 192;
    return 2448 + (rem >> 2) * 48 + (kb * 4 + (rem & 3));
  }
  return rp;
}

// ---------------------------------------------------------------------------
// Kernel 1: split-fp16 MFMA GEMM. R18: GY 16 -> 64. Cold-dispatch counters
// (VALUBusy 5%, MfmaUtil 2.3%, HBM 12.6%) showed it latency-bound with only
// 608 blocks (2.4/CU); 2432 blocks give the scheduler slack to hide
// store/load latency. Per-block M-tile loop runs 2x instead of 8x.
// ---------------------------------------------------------------------------
__global__ __launch_bounds__(256, 2) void hyper_gemm(
    const float* __restrict__ x, const float* __restrict__ c,
    const float* __restrict__ hw1, const float* __restrict__ hb1,
    const float* __restrict__ hw2, const float* __restrict__ hb2,
    float* __restrict__ Pp)
{
  const int t    = threadIdx.x;
  const int lane = t & 63;
  const int wv   = t >> 6;
  const int m16  = lane & 15;
  const int q    = lane >> 4;
  const int rp0  = blockIdx.x * 128;

  const float* wr[2];
  float bias[2];
  #pragma unroll
  for (int nt = 0; nt < 2; ++nt) {
    int rp = rp0 + wv * 32 + nt * 16 + m16;
    int r  = (rp < NP) ? invperm(rp) : 0;
    wr[nt]   = hw2 + (size_t)r * 96;
    bias[nt] = (rp < NP) ? hb2[r] : 0.f;
  }

  f16x8 bh[3][2], bl[3][2];
  #pragma unroll
  for (int ch = 0; ch < 3; ++ch) {
    const int k0 = ch * 32 + q * 8;
    #pragma unroll
    for (int nt = 0; nt < 2; ++nt) {
      float4 f0 = *(const float4*)(wr[nt] + k0);
      float4 f1 = *(const float4*)(wr[nt] + k0 + 4);
      float fv[8] = {f0.x,f0.y,f0.z,f0.w,f1.x,f1.y,f1.z,f1.w};
      #pragma unroll
      for (int e = 0; e < 8; ++e) {
        _Float16 hi = (_Float16)fv[e];
        float r = fv[e] - (float)hi;
        bh[ch][nt][e] = hi;
        bl[ch][nt][e] = (_Float16)r;
      }
    }
  }

  float* cbase = Pp + (size_t)blockIdx.x * NB * 128;

  for (int mtile = blockIdx.y; mtile < 128; mtile += GY) {
    const int i0 = mtile * 64;

    float xv[4], cv[4];
    #pragma unroll
    for (int mt = 0; mt < 4; ++mt) {
      int i = i0 + mt * 16 + m16;
      xv[mt] = x[i]; cv[mt] = c[i];
    }

    f32x4 acc[4][2];
    #pragma unroll
    for (int mt = 0; mt < 4; ++mt)
      #pragma unroll
      for (int nt = 0; nt < 2; ++nt)
        acc[mt][nt] = (f32x4){0.f, 0.f, 0.f, 0.f};

    #pragma unroll
    for (int ch = 0; ch < 3; ++ch) {
      const int k0 = ch * 32 + q * 8;

      float4 A0 = *(const float4*)(hw1 + 2 * k0);
      float4 A1 = *(const float4*)(hw1 + 2 * k0 + 4);
      float4 A2 = *(const float4*)(hw1 + 2 * k0 + 8);
      float4 A3 = *(const float4*)(hw1 + 2 * k0 + 12);
      float4 B0 = *(const float4*)(hb1 + k0);
      float4 B1 = *(const float4*)(hb1 + k0 + 4);
      float w0k[8] = {A0.x,A0.z,A1.x,A1.z,A2.x,A2.z,A3.x,A3.z};
      float w1k[8] = {A0.y,A0.w,A1.y,A1.w,A2.y,A2.w,A3.y,A3.w};
      float bk[8]  = {B0.x,B0.y,B0.z,B0.w,B1.x,B1.y,B1.z,B1.w};

      f16x8 ah[4], al[4];
      #pragma unroll
      for (int mt = 0; mt < 4; ++mt) {
        #pragma unroll
        for (int j = 0; j < 8; ++j) {
          float h = fmaf(xv[mt], w0k[j], fmaf(cv[mt], w1k[j], bk[j]));
          h = h > 0.f ? h : 0.f;
          _Float16 hi = (_Float16)h;
          float r = h - (float)hi;
          ah[mt][j] = hi;
          al[mt][j] = (_Float16)r;
        }
      }

      #pragma unroll
      for (int mt = 0; mt < 4; ++mt)
        #pragma unroll
        for (int nt = 0; nt < 2; ++nt) {
          acc[mt][nt] = __builtin_amdgcn_mfma_f32_16x16x32_f16(al[mt], bl[ch][nt], acc[mt][nt], 0, 0, 0);
          acc[mt][nt] = __builtin_amdgcn_mfma_f32_16x16x32_f16(ah[mt], bl[ch][nt], acc[mt][nt], 0, 0, 0);
          acc[mt][nt] = __builtin_amdgcn_mfma_f32_16x16x32_f16(al[mt], bh[ch][nt], acc[mt][nt], 0, 0, 0);
          acc[mt][nt] = __builtin_amdgcn_mfma_f32_16x16x32_f16(ah[mt], bh[ch][nt], acc[mt][nt], 0, 0, 0);
        }
    }

    #pragma unroll
    for (int nt = 0; nt < 2; ++nt) {
      int off = wv * 32 + nt * 16 + m16;
      if (rp0 + off < NP) {
        #pragma unroll
        for (int mt = 0; mt < 4; ++mt)
          #pragma unroll
          for (int r = 0; r < 4; ++r) {
            int i = i0 + mt * 16 + q * 4 + r;
            cbase[(size_t)i * 128 + off] = acc[mt][nt][r] + bias[nt];
          }
      }
    }
  }
}

// ---------------------------------------------------------------------------
// Kernel 2 (R18): R13's body (validated correct: passed at absmax 0.023) with
// the launch-bound fixed. R13's (64,4) made the allocator clamp to 64 VGPR
// and scratch-spill the 96-reg weight arrays (FETCH 1.08 GB). (64,2) sets
// the cap at 256: the ~108-reg body fits, HW packs 4 waves/SIMD by actual
// usage. Theory: R11/R13 is chain-latency x residency bound (3360 cy/step
// chain; throughput = resident waves / chain) -> 16 waves/CU = 2x R11.
// DS pipe at 16 waves/CU: 16*48 broadcast b128 ~ 2300 cy/CU-step, fits.
// ---------------------------------------------------------------------------

// x += dpp(x) with add-identity for invalid/masked lanes (LLVM reduce pattern)
#define DPP_ADD(x, ctrl, rmask)                                               \
  (x) += __int_as_float(__builtin_amdgcn_update_dpp(                          \
      0, __float_as_int(x), (ctrl), (rmask), 0xf, false))

__global__ __launch_bounds__(64, 2) void adam_inner(
    const float* __restrict__ Pp, float* __restrict__ out)
{
  __shared__ __align__(16) float hd[2][96];   // [buf][h(48)|dh(48)]

  const int lane = threadIdx.x;
  const int i    = blockIdx.x;
  const bool act = lane < NW;

  float* buf0 = &hd[0][0];
  float* buf1 = &hd[1][0];

  float w0  = act ? *pptr(Pp, i, lane)        : 0.f;
  float b0  = act ? *pptr(Pp, i, 48 + lane)   : 0.f;
  float b1v = act ? *pptr(Pp, i, 2400 + lane) : 0.f;
  float b2v = act ? *pptr(Pp, i, 4752 + lane) : 0.f;
  float w3  = act ? *pptr(Pp, i, 4800 + lane) : 0.f;

  f32x2 w1p[24], w2p[24];
  #pragma unroll
  for (int kb = 0; kb < 12; ++kb) {
    float4 q1 = *(const float4*)pptr(Pp, i, 96 + kb * 192 + lane * 4);
    w1p[2 * kb]     = (f32x2){q1.x, q1.y};
    w1p[2 * kb + 1] = (f32x2){q1.z, q1.w};
    float4 q2 = *(const float4*)pptr(Pp, i, 2448 + kb * 192 + lane * 4);
    w2p[2 * kb]     = (f32x2){q2.x, q2.y};
    w2p[2 * kb + 1] = (f32x2){q2.z, q2.w};
  }

  float y = 0.f, m = 0.f, v = 0.f;
  float b1t = 1.f, b2t = 1.f;

  #pragma unroll 1
  for (int t = 0; t < 20; ++t) {
    // ---- layer 0 (scalar input): lane j computes unit j ----
    float z  = fmaf(w0, y, b0);
    float s  = __builtin_amdgcn_rcpf(1.f + __expf(-z));
    float h  = z * s;
    float dh = fmaf(z * s, 1.f - s, s) * w0;
    if (act) { buf0[lane] = h; buf0[48 + lane] = dh; }

    // ---- layer 1: prefetch ALL broadcast reads, then indep chains ----
    float4 ph[12], pd[12];
    #pragma unroll
    for (int kk = 0; kk < 12; ++kk) {
      ph[kk] = *(const float4*)(buf0 + 4 * kk);
      pd[kk] = *(const float4*)(buf0 + 48 + 4 * kk);
    }
    {
      f32x2 zz[4] = {(f32x2){b1v, 0.f}, (f32x2){0.f, 0.f},
                     (f32x2){0.f, 0.f}, (f32x2){0.f, 0.f}};
      f32x2 dd[4] = {(f32x2){0.f, 0.f}, (f32x2){0.f, 0.f},
                     (f32x2){0.f, 0.f}, (f32x2){0.f, 0.f}};
      #pragma unroll
      for (int kk = 0; kk < 12; ++kk) {
        int c0 = (2 * kk) & 3, c1 = (2 * kk + 1) & 3;
        zz[c0] = __builtin_elementwise_fma(w1p[2 * kk],     (f32x2){ph[kk].x, ph[kk].y}, zz[c0]);
        zz[c1] = __builtin_elementwise_fma(w1p[2 * kk + 1], (f32x2){ph[kk].z, ph[kk].w}, zz[c1]);
        dd[c0] = __builtin_elementwise_fma(w1p[2 * kk],     (f32x2){pd[kk].x, pd[kk].y}, dd[c0]);
        dd[c1] = __builtin_elementwise_fma(w1p[2 * kk + 1], (f32x2){pd[kk].z, pd[kk].w}, dd[c1]);
      }
      f32x2 zs = (zz[0] + zz[1]) + (zz[2] + zz[3]);
      f32x2 ds = (dd[0] + dd[1]) + (dd[2] + dd[3]);
      float z1  = zs.x + zs.y;
      float dz1 = ds.x + ds.y;

      s  = __builtin_amdgcn_rcpf(1.f + __expf(-z1));
      h  = z1 * s;
      dh = fmaf(h, 1.f - s, s) * dz1;
    }
    if (act) { buf1[lane] = h; buf1[48 + lane] = dh; }

    // ---- layer 2 ----
    #pragma unroll
    for (int kk = 0; kk < 12; ++kk) {
      ph[kk] = *(const float4*)(buf1 + 4 * kk);
      pd[kk] = *(const float4*)(buf1 + 48 + 4 * kk);
    }
    {
      f32x2 zz[4] = {(f32x2){b2v, 0.f}, (f32x2){0.f, 0.f},
                     (f32x2){0.f, 0.f}, (f32x2){0.f, 0.f}};
      f32x2 dd[4] = {(f32x2){0.f, 0.f}, (f32x2){0.f, 0.f},
                     (f32x2){0.f, 0.f}, (f32x2){0.f, 0.f}};
      #pragma unroll
      for (int kk = 0; kk < 12; ++kk) {
        int c0 = (2 * kk) & 3, c1 = (2 * kk + 1) & 3;
        zz[c0] = __builtin_elementwise_fma(w2p[2 * kk],     (f32x2){ph[kk].x, ph[kk].y}, zz[c0]);
        zz[c1] = __builtin_elementwise_fma(w2p[2 * kk + 1], (f32x2){ph[kk].z, ph[kk].w}, zz[c1]);
        dd[c0] = __builtin_elementwise_fma(w2p[2 * kk],     (f32x2){pd[kk].x, pd[kk].y}, dd[c0]);
        dd[c1] = __builtin_elementwise_fma(w2p[2 * kk + 1], (f32x2){pd[kk].z, pd[kk].w}, dd[c1]);
      }
      f32x2 zs = (zz[0] + zz[1]) + (zz[2] + zz[3]);
      f32x2 ds = (dd[0] + dd[1]) + (dd[2] + dd[3]);
      float z2  = zs.x + zs.y;
      float dz2 = ds.x + ds.y;

      s  = __builtin_amdgcn_rcpf(1.f + __expf(-z2));
      dh = fmaf(z2 * s, 1.f - s, s) * dz2;
    }

    // ---- g = w3 . dh3 : DPP reduction (VALU pipe, no DS ops) ----
    float r = act ? w3 * dh : 0.f;
    DPP_ADD(r, 0x111, 0xf);   // row_shr:1
    DPP_ADD(r, 0x112, 0xf);   // row_shr:2
    DPP_ADD(r, 0x114, 0xf);   // row_shr:4
    DPP_ADD(r, 0x118, 0xf);   // row_shr:8  -> lane15 of each row = row sum
    DPP_ADD(r, 0x142, 0xa);   // row_bcast:15 into rows 1,3
    DPP_ADD(r, 0x143, 0xc);   // row_bcast:31 into rows 2,3 -> lane63 = total
    float g = __int_as_float(__builtin_amdgcn_readlane(__float_as_int(r), 63));

    // ---- Adam update (replicated per lane) ----
    m = fmaf(0.9f,   m, 0.1f   * g);
    v = fmaf(0.999f, v, 0.001f * g * g);
    b1t *= 0.9f; b2t *= 0.999f;
    float mh  = m * __builtin_amdgcn_rcpf(1.f - b1t);
    float vh  = v * __builtin_amdgcn_rcpf(1.f - b2t);
    float den = __builtin_amdgcn_sqrtf(vh) + 1e-8f;
    y -= 0.1f * mh * __builtin_amdgcn_rcpf(den);
  }

  if (lane == 0) out[i] = y;
}

// ---------------------------------------------------------------------------
extern "C" void kernel_launch(void* const* d_in, const int* in_sizes, int n_in,
                              void* d_out, int out_size, void* d_ws, size_t ws_size,
                              hipStream_t stream) {
  const float* x   = (const float*)d_in[0];
  const float* c   = (const float*)d_in[1];
  const float* hw1 = (const float*)d_in[2];
  const float* hb1 = (const float*)d_in[3];
  const float* hw2 = (const float*)d_in[4];
  const float* hb2 = (const float*)d_in[5];
  float* Pp  = (float*)d_ws;   // NCH*NB*128*4 = 159,383,552 bytes
  float* out = (float*)d_out;

  dim3 gridB(NCH, GY);         // 38 x 64 blocks
  hyper_gemm<<<gridB, dim3(256), 0, stream>>>(x, c, hw1, hb1, hw2, hb2, Pp);
  adam_inner<<<dim3(8192), dim3(64), 0, stream>>>(Pp, out);
}